// Round 5
// baseline (30861.612 us; speedup 1.0000x reference)
//
#include <hip/hip_runtime.h>
#include <math.h>

typedef float fv4 __attribute__((ext_vector_type(4)));

#define NSTEP 20
#define HD 512
#define QD 256
#define VOC 128
#define RB 4          // rows per block
#define TPB 512

// numpy-style f32 elementwise ops: correctly-rounded f32 exp/tanh, then
// separately-rounded f32 add/div/mul (no FMA contraction anywhere).
__device__ __forceinline__ float sig_np(float x) {
  float t = (float)exp(-(double)x);              // ~np.exp(f32): corr-rounded
  return __fdiv_rn(1.0f, __fadd_rn(1.0f, t));
}
__device__ __forceinline__ float tanh_np(float x) {
  return (float)tanh((double)x);                 // ~np.tanh(f32)
}

// Strict-f32 LSTM char decoder emulating numpy f32 semantics: per-element
// sequential-k FMA chains, f32 recurrent state. One block owns RB rows;
// thread u owns hidden unit u. Raw weight layouts.
__global__ __launch_bounds__(TPB)
void decoder_f32(const float* __restrict__ quant,
                 const float* __restrict__ w_in,
                 const float* __restrict__ b_in,
                 const float* __restrict__ w_ih,
                 const float* __restrict__ w_hh,
                 const float* __restrict__ b_ih,
                 const float* __restrict__ b_hh,
                 const float* __restrict__ w_out,
                 const float* __restrict__ b_out,
                 float* __restrict__ out) {
  __shared__ float hLDS[RB][HD];        // 8 KB
  __shared__ float logitsLDS[RB][VOC];  // 2 KB
  __shared__ int idxLDS[RB];

  const int u    = threadIdx.x;        // hidden unit 0..511
  const int row0 = blockIdx.x * RB;

  // ---- h0 = quant @ w_in.T + b_in   (sequential-k f32 FMA chain + f32 add)
  {
    const float* wrow = w_in + (size_t)u * QD;
    float a[RB];
#pragma unroll
    for (int r = 0; r < RB; ++r) a[r] = 0.0f;
    for (int k = 0; k < QD; ++k) {
      float wv = wrow[k];
#pragma unroll
      for (int r = 0; r < RB; ++r)
        a[r] = __builtin_fmaf(wv, quant[(size_t)(row0 + r) * QD + k], a[r]);
    }
    float bb = b_in[u];
#pragma unroll
    for (int r = 0; r < RB; ++r) hLDS[r][u] = __fadd_rn(a[r], bb);
  }

  float c[RB];
#pragma unroll
  for (int r = 0; r < RB; ++r) c[r] = 0.0f;
  if (u < RB) idxLDS[u] = 0;           // <start> token

  // bias = b_ih + b_hh (f32 add, as in ref)
  float bias[4];
#pragma unroll
  for (int g = 0; g < 4; ++g)
    bias[g] = __fadd_rn(b_ih[g * HD + u], b_hh[g * HD + u]);

  __syncthreads();

  for (int t = 0; t < NSTEP; ++t) {
    // ---- T2 = h @ w_hh.T : sequential-k f32 FMA chain per gate
    float acc[RB][4];
#pragma unroll
    for (int r = 0; r < RB; ++r)
#pragma unroll
      for (int g = 0; g < 4; ++g) acc[r][g] = 0.0f;

#pragma unroll
    for (int g = 0; g < 4; ++g) {
      const float* wrow = w_hh + (size_t)(g * HD + u) * HD;
      for (int k = 0; k < HD; ++k) {
        float wv = wrow[k];
#pragma unroll
        for (int r = 0; r < RB; ++r)
          acc[r][g] = __builtin_fmaf(wv, hLDS[r][k], acc[r][g]);
      }
    }

    // gates = (T1 + T2) + bias, T1[u] = w_ih[u, ix] (one-hot matmul is exact)
    float hnew[RB];
#pragma unroll
    for (int r = 0; r < RB; ++r) {
      int ix = idxLDS[r];
      float ga[4];
#pragma unroll
      for (int g = 0; g < 4; ++g) {
        float t1 = w_ih[(size_t)(g * HD + u) * VOC + ix];
        ga[g] = __fadd_rn(__fadd_rn(t1, acc[r][g]), bias[g]);
      }
      // ---- elementwise (i,f,g,o): separately-rounded f32 ops
      float ig = sig_np(ga[0]);
      float fg = sig_np(ga[1]);
      float gg = tanh_np(ga[2]);
      float og = sig_np(ga[3]);
      c[r] = __fadd_rn(__fmul_rn(fg, c[r]), __fmul_rn(ig, gg));
      hnew[r] = __fmul_rn(og, tanh_np(c[r]));
    }
    __syncthreads();                   // done reading h_{t-1}
#pragma unroll
    for (int r = 0; r < RB; ++r) hLDS[r][u] = hnew[r];
    __syncthreads();                   // h_t visible

    // ---- logits = h @ w_out.T + b_out : thread u -> (row u>>7, vocab u&127)
    {
      int r = u >> 7, v = u & (VOC - 1);
      const float* wrow = w_out + (size_t)v * HD;
      float a = 0.0f;
      for (int k = 0; k < HD; ++k)
        a = __builtin_fmaf(wrow[k], hLDS[r][k], a);
      a = __fadd_rn(a, b_out[v]);
      logitsLDS[r][v] = a;
      out[(size_t)((row0 + r) * NSTEP + t) * VOC + v] = a;
    }
    __syncthreads();

    // ---- argmax (first max) per row, sequential f32 scan (np.argmax)
    if (u < RB) {
      float mv = logitsLDS[u][0];
      int mi = 0;
      for (int v = 1; v < VOC; ++v) {
        float x = logitsLDS[u][v];
        if (x > mv) { mv = x; mi = v; }
      }
      idxLDS[u] = mi;
    }
    __syncthreads();                   // idx ready for step t+1
  }
}

extern "C" void kernel_launch(void* const* d_in, const int* in_sizes, int n_in,
                              void* d_out, int out_size, void* d_ws, size_t ws_size,
                              hipStream_t stream) {
  const float* quant = (const float*)d_in[0];
  const float* w_in  = (const float*)d_in[1];
  const float* b_in  = (const float*)d_in[2];
  const float* w_ih  = (const float*)d_in[3];
  const float* w_hh  = (const float*)d_in[4];
  const float* b_ih  = (const float*)d_in[5];
  const float* b_hh  = (const float*)d_in[6];
  const float* w_out = (const float*)d_in[7];
  const float* b_out = (const float*)d_in[8];
  float* out = (float*)d_out;

  decoder_f32<<<8192 / RB, TPB, 0, stream>>>(quant, w_in, b_in, w_ih, w_hh,
                                             b_ih, b_hh, w_out, b_out, out);
}

// Round 6
// 7161.148 us; speedup vs baseline: 4.3096x; 4.3096x over previous
//
#include <hip/hip_runtime.h>
#include <math.h>

typedef float fv4 __attribute__((ext_vector_type(4)));

#define NSTEP 20
#define HD 512
#define QD 256
#define VOC 128
#define RB 16         // rows per block
#define TPB 512

// ws layout (float offsets)
#define WG_OFF   0          // [kb=128][g=4][u=512][ki=4] = 1048576 floats (4 MB)
#define WIH_OFF  1048576    // [x=128][g=4][u=512]        = 262144
#define WIN_OFF  1310720    // [kb=64][u=512][ki=4]       = 131072
#define WOUT_OFF 1441792    // [kb=128][v=128][ki=4]      = 65536

// numpy-style f32 elementwise ops (verbatim from the passing round-5 kernel).
__device__ __forceinline__ float sig_np(float x) {
  float t = (float)exp(-(double)x);              // corr-rounded f32 exp
  return __fdiv_rn(1.0f, __fadd_rn(1.0f, t));
}
__device__ __forceinline__ float tanh_np(float x) {
  return (float)tanh((double)x);
}

// Repack weights into lane-contiguous layouts (pure data movement; the values
// feeding each FMA chain are unchanged, so the trajectory stays bit-identical).
__global__ void repack_kernel(const float* __restrict__ w_in,
                              const float* __restrict__ w_ih,
                              const float* __restrict__ w_hh,
                              const float* __restrict__ w_out,
                              float* __restrict__ ws) {
  int t = blockIdx.x * blockDim.x + threadIdx.x;
  {
    // Wg[kb][g][u][ki] = w_hh[(g*512+u)*512 + kb*4+ki]
    int ki = t & 3, u = (t >> 2) & 511, g = (t >> 11) & 3, kb = t >> 13;
    ws[WG_OFF + t] = w_hh[(size_t)(g * HD + u) * HD + kb * 4 + ki];
  }
  if (t < 262144) {
    // Wih[x][g][u] = w_ih[(g*512+u)*128 + x]
    int u = t & 511, g = (t >> 9) & 3, x = t >> 11;
    ws[WIH_OFF + t] = w_ih[(size_t)(g * HD + u) * VOC + x];
  }
  if (t < 131072) {
    // Win[kb][u][ki] = w_in[u*256 + kb*4+ki]
    int ki = t & 3, u = (t >> 2) & 511, kb = t >> 11;
    ws[WIN_OFF + t] = w_in[(size_t)u * QD + kb * 4 + ki];
  }
  if (t < 65536) {
    // Wout[kb][v][ki] = w_out[v*512 + kb*4+ki]
    int ki = t & 3, v = (t >> 2) & 127, kb = t >> 9;
    ws[WOUT_OFF + t] = w_out[(size_t)v * HD + kb * 4 + ki];
  }
}

// Persistent LSTM decoder; thread u owns hidden unit u for RB rows.
// All per-accumulator FMA chains are sequential in k (ki innermost, kb
// ascending) => bit-identical to the verified round-5 trajectory.
__global__ __launch_bounds__(TPB, 4)
void decoder_fast(const float* __restrict__ quant,
                  const float* __restrict__ b_in,
                  const float* __restrict__ b_ih,
                  const float* __restrict__ b_hh,
                  const float* __restrict__ b_out,
                  const float* __restrict__ ws,
                  float* __restrict__ out) {
  __shared__ __align__(16) float hLDS[RB * HD];     // 32 KB
  __shared__ __align__(16) float scratch[RB * QD];  // 16 KB: quant, then logits
  __shared__ int idxLDS[RB];

  const int tid  = threadIdx.x;   // hidden unit 0..511
  const int row0 = blockIdx.x * RB;

  const fv4* Wg4   = (const fv4*)(ws + WG_OFF);
  const float* Wih = ws + WIH_OFF;
  const fv4* Win4  = (const fv4*)(ws + WIN_OFF);
  const fv4* Wout4 = (const fv4*)(ws + WOUT_OFF);
  const fv4* hLDS4 = (const fv4*)hLDS;
  const fv4* q4    = (const fv4*)scratch;

  // stage quant rows (RB*QD = 4096 floats = 1024 fv4), coalesced
  {
    const fv4* src = (const fv4*)(quant + (size_t)row0 * QD);
    fv4* dst = (fv4*)scratch;
    dst[tid]       = src[tid];
    dst[tid + TPB] = src[tid + TPB];
  }
  if (tid < RB) idxLDS[tid] = 0;  // <start> token

  float bias[4];
#pragma unroll
  for (int g = 0; g < 4; ++g)
    bias[g] = __fadd_rn(b_ih[g * HD + tid], b_hh[g * HD + tid]);
  const float bout = b_out[tid & (VOC - 1)];
  const float binu = b_in[tid];

  __syncthreads();

  // ---- h0 = quant @ w_in.T + b_in (sequential-k fmaf chain)
  {
    float a[RB];
#pragma unroll
    for (int r = 0; r < RB; ++r) a[r] = 0.0f;
    for (int kb = 0; kb < QD / 4; ++kb) {
      fv4 w = Win4[kb * 512 + tid];
#pragma unroll
      for (int r = 0; r < RB; ++r) {
        fv4 qv = q4[r * 64 + kb];
        a[r] = __builtin_fmaf(w[0], qv[0], a[r]);
        a[r] = __builtin_fmaf(w[1], qv[1], a[r]);
        a[r] = __builtin_fmaf(w[2], qv[2], a[r]);
        a[r] = __builtin_fmaf(w[3], qv[3], a[r]);
      }
    }
#pragma unroll
    for (int r = 0; r < RB; ++r) hLDS[r * HD + tid] = __fadd_rn(a[r], binu);
  }

  float c[RB];
#pragma unroll
  for (int r = 0; r < RB; ++r) c[r] = 0.0f;

  __syncthreads();

  for (int t = 0; t < NSTEP; ++t) {
    // ---- T2 = h @ w_hh.T, sequential-k chains, coalesced weight loads
    float acc[RB][4];
#pragma unroll
    for (int r = 0; r < RB; ++r)
#pragma unroll
      for (int g = 0; g < 4; ++g) acc[r][g] = 0.0f;

    for (int kb = 0; kb < HD / 4; ++kb) {
      fv4 wv[4];
#pragma unroll
      for (int g = 0; g < 4; ++g) wv[g] = Wg4[(kb * 4 + g) * 512 + tid];
#pragma unroll
      for (int r = 0; r < RB; ++r) {
        fv4 hv = hLDS4[r * 128 + kb];  // broadcast b128
#pragma unroll
        for (int g = 0; g < 4; ++g) {
          acc[r][g] = __builtin_fmaf(wv[g][0], hv[0], acc[r][g]);
          acc[r][g] = __builtin_fmaf(wv[g][1], hv[1], acc[r][g]);
          acc[r][g] = __builtin_fmaf(wv[g][2], hv[2], acc[r][g]);
          acc[r][g] = __builtin_fmaf(wv[g][3], hv[3], acc[r][g]);
        }
      }
    }

    // ---- gates + elementwise (verbatim round-5 numerics)
    float hnew[RB];
#pragma unroll
    for (int r = 0; r < RB; ++r) {
      int ix = idxLDS[r];
      float ga[4];
#pragma unroll
      for (int g = 0; g < 4; ++g) {
        float t1 = Wih[(ix * 4 + g) * 512 + tid];
        ga[g] = __fadd_rn(__fadd_rn(t1, acc[r][g]), bias[g]);
      }
      float ig = sig_np(ga[0]);
      float fg = sig_np(ga[1]);
      float gg = tanh_np(ga[2]);
      float og = sig_np(ga[3]);
      c[r] = __fadd_rn(__fmul_rn(fg, c[r]), __fmul_rn(ig, gg));
      hnew[r] = __fmul_rn(og, tanh_np(c[r]));
    }
    __syncthreads();                 // done reading h_{t-1}
#pragma unroll
    for (int r = 0; r < RB; ++r) hLDS[r * HD + tid] = hnew[r];
    __syncthreads();                 // h_t visible

    // ---- logits: thread -> (v = tid&127, rows rq*4..rq*4+3), seq-k chains
    {
      int v = tid & (VOC - 1), rq = tid >> 7;
      float la[4];
#pragma unroll
      for (int j = 0; j < 4; ++j) la[j] = 0.0f;
      for (int kb = 0; kb < HD / 4; ++kb) {
        fv4 wv = Wout4[kb * 128 + v];
#pragma unroll
        for (int j = 0; j < 4; ++j) {
          fv4 hv = hLDS4[(rq * 4 + j) * 128 + kb];  // broadcast (rq wave-uniform)
          la[j] = __builtin_fmaf(wv[0], hv[0], la[j]);
          la[j] = __builtin_fmaf(wv[1], hv[1], la[j]);
          la[j] = __builtin_fmaf(wv[2], hv[2], la[j]);
          la[j] = __builtin_fmaf(wv[3], hv[3], la[j]);
        }
      }
      float* lg = scratch;  // reuse as logits [RB][VOC]
#pragma unroll
      for (int j = 0; j < 4; ++j) {
        int r = rq * 4 + j;
        float val = __fadd_rn(la[j], bout);
        lg[r * VOC + v] = val;
        out[(size_t)((row0 + r) * NSTEP + t) * VOC + v] = val;
      }
    }
    __syncthreads();

    // ---- argmax (first max) per row, sequential f32 scan (np.argmax)
    if (tid < RB) {
      const float* lg = scratch + tid * VOC;
      float mv = lg[0];
      int mi = 0;
      for (int v = 1; v < VOC; ++v) {
        float x = lg[v];
        if (x > mv) { mv = x; mi = v; }
      }
      idxLDS[tid] = mi;
    }
    __syncthreads();                 // idx ready for step t+1
  }
}

extern "C" void kernel_launch(void* const* d_in, const int* in_sizes, int n_in,
                              void* d_out, int out_size, void* d_ws, size_t ws_size,
                              hipStream_t stream) {
  const float* quant = (const float*)d_in[0];
  const float* w_in  = (const float*)d_in[1];
  const float* b_in  = (const float*)d_in[2];
  const float* w_ih  = (const float*)d_in[3];
  const float* w_hh  = (const float*)d_in[4];
  const float* b_ih  = (const float*)d_in[5];
  const float* b_hh  = (const float*)d_in[6];
  const float* w_out = (const float*)d_in[7];
  const float* b_out = (const float*)d_in[8];
  float* out = (float*)d_out;
  float* ws  = (float*)d_ws;

  repack_kernel<<<4096, 256, 0, stream>>>(w_in, w_ih, w_hh, w_out, ws);
  decoder_fast<<<8192 / RB, TPB, 0, stream>>>(quant, b_in, b_ih, b_hh, b_out,
                                              ws, out);
}

// Round 7
// 7028.764 us; speedup vs baseline: 4.3908x; 1.0188x over previous
//
#include <hip/hip_runtime.h>
#include <math.h>

typedef float fv4 __attribute__((ext_vector_type(4)));

#define NSTEP 20
#define HD 512
#define QD 256
#define VOC 128
#define RB 16         // rows per block
#define TPB 512

// ws layout (float offsets)
#define WG_OFF   0          // [kb=128][g=4][u=512][ki=4] = 1048576 floats (4 MB)
#define WIH_OFF  1048576    // [x=128][g=4][u=512]        = 262144
#define WIN_OFF  1310720    // [kb=64][u=512][ki=4]       = 131072
#define WOUT_OFF 1441792    // [kb=128][v=128][ki=4]      = 65536

// numpy-style f32 elementwise ops (verbatim from the passing round-5 kernel).
__device__ __forceinline__ float sig_np(float x) {
  float t = (float)exp(-(double)x);              // corr-rounded f32 exp
  return __fdiv_rn(1.0f, __fadd_rn(1.0f, t));
}
__device__ __forceinline__ float tanh_np(float x) {
  return (float)tanh((double)x);
}

// Repack weights into lane-contiguous layouts (pure data movement; the values
// feeding each FMA chain are unchanged, so the trajectory stays bit-identical).
__global__ void repack_kernel(const float* __restrict__ w_in,
                              const float* __restrict__ w_ih,
                              const float* __restrict__ w_hh,
                              const float* __restrict__ w_out,
                              float* __restrict__ ws) {
  int t = blockIdx.x * blockDim.x + threadIdx.x;
  {
    // Wg[kb][g][u][ki] = w_hh[(g*512+u)*512 + kb*4+ki]
    int ki = t & 3, u = (t >> 2) & 511, g = (t >> 11) & 3, kb = t >> 13;
    ws[WG_OFF + t] = w_hh[(size_t)(g * HD + u) * HD + kb * 4 + ki];
  }
  if (t < 262144) {
    // Wih[x][g][u] = w_ih[(g*512+u)*128 + x]
    int u = t & 511, g = (t >> 9) & 3, x = t >> 11;
    ws[WIH_OFF + t] = w_ih[(size_t)(g * HD + u) * VOC + x];
  }
  if (t < 131072) {
    // Win[kb][u][ki] = w_in[u*256 + kb*4+ki]
    int ki = t & 3, u = (t >> 2) & 511, kb = t >> 11;
    ws[WIN_OFF + t] = w_in[(size_t)u * QD + kb * 4 + ki];
  }
  if (t < 65536) {
    // Wout[kb][v][ki] = w_out[v*512 + kb*4+ki]
    int ki = t & 3, v = (t >> 2) & 127, kb = t >> 9;
    ws[WOUT_OFF + t] = w_out[(size_t)v * HD + kb * 4 + ki];
  }
}

// Persistent LSTM decoder; thread u owns hidden unit u for RB rows.
// All per-accumulator FMA chains are sequential in k (ki innermost, kb
// ascending) => bit-identical to the verified round-5 trajectory.
// __launch_bounds__(512, 2): VGPR cap >=128 so the ~100-reg accumulator tile
// does NOT spill (round 6's (512,4) capped at 64 VGPR -> 500 MB spill traffic).
__global__ __launch_bounds__(TPB, 2)
void decoder_fast(const float* __restrict__ quant,
                  const float* __restrict__ b_in,
                  const float* __restrict__ b_ih,
                  const float* __restrict__ b_hh,
                  const float* __restrict__ b_out,
                  const float* __restrict__ ws,
                  float* __restrict__ out) {
  __shared__ __align__(16) float hLDS[RB * HD];     // 32 KB
  __shared__ __align__(16) float scratch[RB * QD];  // 16 KB: quant, then logits
  __shared__ int idxLDS[RB];

  const int tid  = threadIdx.x;   // hidden unit 0..511
  const int row0 = blockIdx.x * RB;

  const fv4* Wg4   = (const fv4*)(ws + WG_OFF);
  const float* Wih = ws + WIH_OFF;
  const fv4* Win4  = (const fv4*)(ws + WIN_OFF);
  const fv4* Wout4 = (const fv4*)(ws + WOUT_OFF);
  const fv4* hLDS4 = (const fv4*)hLDS;
  const fv4* q4    = (const fv4*)scratch;

  // stage quant rows (RB*QD = 4096 floats = 1024 fv4), coalesced
  {
    const fv4* src = (const fv4*)(quant + (size_t)row0 * QD);
    fv4* dst = (fv4*)scratch;
    dst[tid]       = src[tid];
    dst[tid + TPB] = src[tid + TPB];
  }
  if (tid < RB) idxLDS[tid] = 0;  // <start> token

  float bias[4];
#pragma unroll
  for (int g = 0; g < 4; ++g)
    bias[g] = __fadd_rn(b_ih[g * HD + tid], b_hh[g * HD + tid]);
  const float bout = b_out[tid & (VOC - 1)];
  const float binu = b_in[tid];

  __syncthreads();

  // ---- h0 = quant @ w_in.T + b_in (sequential-k fmaf chain)
  {
    float a[RB];
#pragma unroll
    for (int r = 0; r < RB; ++r) a[r] = 0.0f;
    for (int kb = 0; kb < QD / 4; ++kb) {
      fv4 w = Win4[kb * 512 + tid];
#pragma unroll
      for (int r = 0; r < RB; ++r) {
        fv4 qv = q4[r * 64 + kb];
        a[r] = __builtin_fmaf(w[0], qv[0], a[r]);
        a[r] = __builtin_fmaf(w[1], qv[1], a[r]);
        a[r] = __builtin_fmaf(w[2], qv[2], a[r]);
        a[r] = __builtin_fmaf(w[3], qv[3], a[r]);
      }
    }
#pragma unroll
    for (int r = 0; r < RB; ++r) hLDS[r * HD + tid] = __fadd_rn(a[r], binu);
  }

  float c[RB];
#pragma unroll
  for (int r = 0; r < RB; ++r) c[r] = 0.0f;

  __syncthreads();

  for (int t = 0; t < NSTEP; ++t) {
    // ---- T2 = h @ w_hh.T, sequential-k chains, coalesced weight loads
    float acc[RB][4];
#pragma unroll
    for (int r = 0; r < RB; ++r)
#pragma unroll
      for (int g = 0; g < 4; ++g) acc[r][g] = 0.0f;

    for (int kb = 0; kb < HD / 4; ++kb) {
      fv4 wv[4];
#pragma unroll
      for (int g = 0; g < 4; ++g) wv[g] = Wg4[(kb * 4 + g) * 512 + tid];
#pragma unroll
      for (int r = 0; r < RB; ++r) {
        fv4 hv = hLDS4[r * 128 + kb];  // broadcast b128
#pragma unroll
        for (int g = 0; g < 4; ++g) {
          acc[r][g] = __builtin_fmaf(wv[g][0], hv[0], acc[r][g]);
          acc[r][g] = __builtin_fmaf(wv[g][1], hv[1], acc[r][g]);
          acc[r][g] = __builtin_fmaf(wv[g][2], hv[2], acc[r][g]);
          acc[r][g] = __builtin_fmaf(wv[g][3], hv[3], acc[r][g]);
        }
      }
    }

    // ---- gates + elementwise (verbatim round-5 numerics)
    float hnew[RB];
#pragma unroll
    for (int r = 0; r < RB; ++r) {
      int ix = idxLDS[r];
      float ga[4];
#pragma unroll
      for (int g = 0; g < 4; ++g) {
        float t1 = Wih[(ix * 4 + g) * 512 + tid];
        ga[g] = __fadd_rn(__fadd_rn(t1, acc[r][g]), bias[g]);
      }
      float ig = sig_np(ga[0]);
      float fg = sig_np(ga[1]);
      float gg = tanh_np(ga[2]);
      float og = sig_np(ga[3]);
      c[r] = __fadd_rn(__fmul_rn(fg, c[r]), __fmul_rn(ig, gg));
      hnew[r] = __fmul_rn(og, tanh_np(c[r]));
    }
    __syncthreads();                 // done reading h_{t-1}
#pragma unroll
    for (int r = 0; r < RB; ++r) hLDS[r * HD + tid] = hnew[r];
    __syncthreads();                 // h_t visible

    // ---- logits: thread -> (v = tid&127, rows rq*4..rq*4+3), seq-k chains
    {
      int v = tid & (VOC - 1), rq = tid >> 7;
      float la[4];
#pragma unroll
      for (int j = 0; j < 4; ++j) la[j] = 0.0f;
      for (int kb = 0; kb < HD / 4; ++kb) {
        fv4 wv = Wout4[kb * 128 + v];
#pragma unroll
        for (int j = 0; j < 4; ++j) {
          fv4 hv = hLDS4[(rq * 4 + j) * 128 + kb];  // broadcast (rq wave-uniform)
          la[j] = __builtin_fmaf(wv[0], hv[0], la[j]);
          la[j] = __builtin_fmaf(wv[1], hv[1], la[j]);
          la[j] = __builtin_fmaf(wv[2], hv[2], la[j]);
          la[j] = __builtin_fmaf(wv[3], hv[3], la[j]);
        }
      }
      float* lg = scratch;  // reuse as logits [RB][VOC]
#pragma unroll
      for (int j = 0; j < 4; ++j) {
        int r = rq * 4 + j;
        float val = __fadd_rn(la[j], bout);
        lg[r * VOC + v] = val;
        out[(size_t)((row0 + r) * NSTEP + t) * VOC + v] = val;
      }
    }
    __syncthreads();

    // ---- argmax (first max) per row, sequential f32 scan (np.argmax)
    if (tid < RB) {
      const float* lg = scratch + tid * VOC;
      float mv = lg[0];
      int mi = 0;
      for (int v = 1; v < VOC; ++v) {
        float x = lg[v];
        if (x > mv) { mv = x; mi = v; }
      }
      idxLDS[tid] = mi;
    }
    __syncthreads();                 // idx ready for step t+1
  }
}

extern "C" void kernel_launch(void* const* d_in, const int* in_sizes, int n_in,
                              void* d_out, int out_size, void* d_ws, size_t ws_size,
                              hipStream_t stream) {
  const float* quant = (const float*)d_in[0];
  const float* w_in  = (const float*)d_in[1];
  const float* b_in  = (const float*)d_in[2];
  const float* w_ih  = (const float*)d_in[3];
  const float* w_hh  = (const float*)d_in[4];
  const float* b_ih  = (const float*)d_in[5];
  const float* b_hh  = (const float*)d_in[6];
  const float* w_out = (const float*)d_in[7];
  const float* b_out = (const float*)d_in[8];
  float* out = (float*)d_out;
  float* ws  = (float*)d_ws;

  repack_kernel<<<4096, 256, 0, stream>>>(w_in, w_ih, w_hh, w_out, ws);
  decoder_fast<<<8192 / RB, TPB, 0, stream>>>(quant, b_in, b_ih, b_hh, b_out,
                                              ws, out);
}